// Round 14
// baseline (692.310 us; speedup 1.0000x reference)
//
#include <hip/hip_runtime.h>
#include <math.h>

#define NN 100000
#define NE 600000
#define DD 128
#define NBIN 782           // ceil(NN/128) coarse bins (128 nodes each)
#define BCAP 1152          // slab capacity per bin (mean 767, +13.9 sigma)
#define SORTB 128          // sort blocks
#define EPB 4688           // ceil(NE/SORTB)
#define NTILES 6250        // NN/16
#define TPB 8              // row-tiles per block (GEMM)
#define RS 132             // LDS accum row stride (floats), breaks bank alias

typedef __attribute__((ext_vector_type(8))) __bf16 bf16x8;
typedef __attribute__((ext_vector_type(4))) float f32x4;

__device__ inline unsigned short f2bf(float f) {
    unsigned int u = __float_as_uint(f);
    unsigned int r = (u + 0x7fffu + ((u >> 16) & 1u)) >> 16;
    return (unsigned short)r;
}

// ---------------- coarse bucket sort (LDS) + weight staging ----------------
// blocks [0,SORTB): sort 4688 edges by bin=dst>>7 in LDS, flush coalesced
// runs to per-bin slabs. blocks [SORTB, SORTB+128): stage WT bf16.
__global__ __launch_bounds__(256) void sort_wt_kernel(
    const int* __restrict__ ei,
    const float* __restrict__ Wl2, const float* __restrict__ Wr2,
    unsigned short* __restrict__ WT,
    int* __restrict__ cursor, int* __restrict__ slab)
{
    if (blockIdx.x >= SORTB) {          // ---- weight staging ----
        int t = (blockIdx.x - SORTB) * 256 + threadIdx.x;   // 0..32767
        int n = t >> 8, k = t & 255;
        float v = (k < DD) ? Wl2[n * DD + k] : Wr2[n * DD + (k - DD)];
        WT[t] = f2bf(v);
        return;
    }

    __shared__ int hist[NBIN];
    __shared__ int binStart[NBIN];   // local exclusive scan
    __shared__ int binBase[NBIN];    // global slab base for this block
    __shared__ int lcur[NBIN];
    __shared__ int stage[EPB];       // packed (src<<7)|(dst&127), 18.75 KB
    __shared__ int scan_tmp[256];
    __shared__ int carry;

    const int tid = threadIdx.x;
    const int e0  = blockIdx.x * EPB;
    const int cnt = min(EPB, NE - e0);

    for (int i = tid; i < NBIN; i += 256) hist[i] = 0;
    if (tid == 0) carry = 0;
    __syncthreads();

    // pass 1: local histogram over coarse bins
    for (int i = tid; i < cnt; i += 256) {
        int d = ei[NE + e0 + i];
        atomicAdd(&hist[d >> 7], 1);
    }
    __syncthreads();

    // block-wide exclusive scan over NBIN (chunks of 256 with carry)
    for (int c = 0; c < NBIN; c += 256) {
        int idx = c + tid;
        int v = (idx < NBIN) ? hist[idx] : 0;
        scan_tmp[tid] = v;
        __syncthreads();
        for (int off = 1; off < 256; off <<= 1) {
            int t2 = (tid >= off) ? scan_tmp[tid - off] : 0;
            __syncthreads();
            scan_tmp[tid] += t2;
            __syncthreads();
        }
        if (idx < NBIN) {
            int ex = carry + scan_tmp[tid] - v;
            binStart[idx] = ex;
            lcur[idx] = ex;
        }
        __syncthreads();
        if (tid == 0) carry += scan_tmp[255];
        __syncthreads();
    }

    // reserve global slab space: ~782 atomics per block (not per edge)
    for (int b = tid; b < NBIN; b += 256) {
        int h = hist[b];
        binBase[b] = (h > 0) ? atomicAdd(&cursor[b], h) : 0;
    }
    __syncthreads();

    // pass 2: place edges into LDS sorted-by-bin
    for (int i = tid; i < cnt; i += 256) {
        int s = ei[e0 + i];
        int d = ei[NE + e0 + i];
        int b = d >> 7;
        int p = atomicAdd(&lcur[b], 1);
        stage[p] = (s << 7) | (d & 127);
    }
    __syncthreads();

    // flush: consecutive LDS positions in a bin -> consecutive global addrs
    for (int p = tid; p < cnt; p += 256) {
        int w = stage[p];
        int b = (w >> 7) >> 7;           // src>>7? no: recompute bin from dst
        // NOTE: w = (src<<7)|dlow; bin is NOT recoverable from w alone.
        // (handled below via binStart search-free trick)
        (void)b;
    }
    // Recoverable flush: iterate bins owned by strided threads is slow;
    // instead re-walk edges: positions are deterministic via lcur reset.
    __syncthreads();
    // reset lcur to binStart and replay placement to get (p -> global) map
    for (int b2 = tid; b2 < NBIN; b2 += 256) lcur[b2] = binStart[b2];
    __syncthreads();
    for (int i = tid; i < cnt; i += 256) {
        int d = ei[NE + e0 + i];
        int b2 = d >> 7;
        int p = atomicAdd(&lcur[b2], 1);
        int g = binBase[b2] + (p - binStart[b2]);
        slab[b2 * BCAP + g] = stage[p];
    }
}

// ---------------- bin aggregation: LDS f32 accum per 128-node bin ----------------
__global__ __launch_bounds__(256) void bin_aggregate_kernel(
    const float* __restrict__ x, const int* __restrict__ cursor,
    const int* __restrict__ slab,
    const float* __restrict__ bn_gamma, const float* __restrict__ bn_beta,
    const float* __restrict__ bn_mean, const float* __restrict__ bn_var,
    unsigned short* __restrict__ A)
{
    __shared__ float acc[128 * RS];   // 67.6 KB
    __shared__ float degs[128];

    const int tid   = threadIdx.x;
    const int bin   = blockIdx.x;
    const int node0 = bin << 7;

    {
        const float4 z4 = {0.f, 0.f, 0.f, 0.f};
        for (int i = tid * 4; i < 128 * RS; i += 1024) *(float4*)&acc[i] = z4;
        for (int i = tid; i < 128; i += 256) degs[i] = 0.f;
    }
    __syncthreads();

    const int cnt = cursor[bin];
    const int* sp = slab + bin * BCAP;
    const int g = tid >> 5;          // 8 groups
    const int l = tid & 31;
    const int c = l * 4;
    const float* xb = x + c;

    // main: 4-edge chunks per group (chunk id g + 8k), unrolled for MLP
    int j0 = g * 4;
    for (; j0 + 4 <= cnt; j0 += 32) {
        int w0 = sp[j0], w1 = sp[j0 + 1], w2 = sp[j0 + 2], w3 = sp[j0 + 3];
        float4 v0 = *(const float4*)(xb + (size_t)(w0 >> 7) * DD);
        float4 v1 = *(const float4*)(xb + (size_t)(w1 >> 7) * DD);
        float4 v2 = *(const float4*)(xb + (size_t)(w2 >> 7) * DD);
        float4 v3 = *(const float4*)(xb + (size_t)(w3 >> 7) * DD);
        float* r0 = &acc[(w0 & 127) * RS + c];
        float* r1 = &acc[(w1 & 127) * RS + c];
        float* r2 = &acc[(w2 & 127) * RS + c];
        float* r3 = &acc[(w3 & 127) * RS + c];
        atomicAdd(r0 + 0, fmaxf(v0.x, 0.f)); atomicAdd(r0 + 1, fmaxf(v0.y, 0.f));
        atomicAdd(r0 + 2, fmaxf(v0.z, 0.f)); atomicAdd(r0 + 3, fmaxf(v0.w, 0.f));
        atomicAdd(r1 + 0, fmaxf(v1.x, 0.f)); atomicAdd(r1 + 1, fmaxf(v1.y, 0.f));
        atomicAdd(r1 + 2, fmaxf(v1.z, 0.f)); atomicAdd(r1 + 3, fmaxf(v1.w, 0.f));
        atomicAdd(r2 + 0, fmaxf(v2.x, 0.f)); atomicAdd(r2 + 1, fmaxf(v2.y, 0.f));
        atomicAdd(r2 + 2, fmaxf(v2.z, 0.f)); atomicAdd(r2 + 3, fmaxf(v2.w, 0.f));
        atomicAdd(r3 + 0, fmaxf(v3.x, 0.f)); atomicAdd(r3 + 1, fmaxf(v3.y, 0.f));
        atomicAdd(r3 + 2, fmaxf(v3.z, 0.f)); atomicAdd(r3 + 3, fmaxf(v3.w, 0.f));
        if (l == 0) {
            atomicAdd(&degs[w0 & 127], 1.f);
            atomicAdd(&degs[w1 & 127], 1.f);
            atomicAdd(&degs[w2 & 127], 1.f);
            atomicAdd(&degs[w3 & 127], 1.f);
        }
    }
    // tail: partial chunk owned by one group
    {
        int jt = cnt & ~3;
        if (jt < cnt && ((jt >> 2) & 7) == g) {
            for (int j = jt; j < cnt; ++j) {
                int w = sp[j];
                float4 v = *(const float4*)(xb + (size_t)(w >> 7) * DD);
                float* r = &acc[(w & 127) * RS + c];
                atomicAdd(r + 0, fmaxf(v.x, 0.f)); atomicAdd(r + 1, fmaxf(v.y, 0.f));
                atomicAdd(r + 2, fmaxf(v.z, 0.f)); atomicAdd(r + 3, fmaxf(v.w, 0.f));
                if (l == 0) atomicAdd(&degs[w & 127], 1.f);
            }
        }
    }
    __syncthreads();

    // write phase: thread owns half a row
    const int row  = tid >> 1;
    const int node = node0 + row;
    if (node < NN) {
        const int cb = (tid & 1) * 64;
        const float dg = degs[row];
        const float inv = (dg > 0.f) ? 1.0f / dg : 0.f;
        unsigned short* arow = A + (size_t)node * 256;
        for (int k = cb; k < cb + 64; k += 4) {
            const float4 bm = *(const float4*)(bn_mean  + k);
            const float4 bv = *(const float4*)(bn_var   + k);
            const float4 bg = *(const float4*)(bn_gamma + k);
            const float4 bb = *(const float4*)(bn_beta  + k);
            const float s0 = rsqrtf(bv.x + 1e-5f) * bg.x;
            const float s1 = rsqrtf(bv.y + 1e-5f) * bg.y;
            const float s2 = rsqrtf(bv.z + 1e-5f) * bg.z;
            const float s3 = rsqrtf(bv.w + 1e-5f) * bg.w;
            const float4 a4 = *(const float4*)&acc[row * RS + k];
            float m0, m1, m2, m3;
            if (dg > 0.f) {
                m0 = (a4.x * inv - bm.x) * s0 + bb.x;
                m1 = (a4.y * inv - bm.y) * s1 + bb.y;
                m2 = (a4.z * inv - bm.z) * s2 + bb.z;
                m3 = (a4.w * inv - bm.w) * s3 + bb.w;
            } else {
                m0 = m1 = m2 = m3 = 0.f;
            }
            const float4 xv = *(const float4*)(x + (size_t)node * DD + k);
            float h0 = (fmaxf(xv.x, 0.f) - bm.x) * s0 + bb.x;
            float h1 = (fmaxf(xv.y, 0.f) - bm.y) * s1 + bb.y;
            float h2 = (fmaxf(xv.z, 0.f) - bm.z) * s2 + bb.z;
            float h3 = (fmaxf(xv.w, 0.f) - bm.w) * s3 + bb.w;
            ushort4 mm; mm.x = f2bf(m0); mm.y = f2bf(m1); mm.z = f2bf(m2); mm.w = f2bf(m3);
            ushort4 hh; hh.x = f2bf(h0); hh.y = f2bf(h1); hh.z = f2bf(h2); hh.w = f2bf(h3);
            *(ushort4*)(arow + k)      = mm;
            *(ushort4*)(arow + DD + k) = hh;
        }
    }
}

// ---------------- MFMA GEMM + bias + L2 normalize (B-resident) [r11: <=58us] ----------------
__global__ __launch_bounds__(256) void mfma_gemm_norm_kernel(
    const unsigned short* __restrict__ A, const unsigned short* __restrict__ WT,
    const float* __restrict__ bl, float* __restrict__ out)
{
    __shared__ float partial[4][16];

    const int wave = threadIdx.x >> 6;
    const int l    = threadIdx.x & 63;
    const int r    = l & 15;
    const int seg  = l >> 4;
    const int c0   = wave * 32;

    bf16x8 bf0[8], bf1[8];
    {
        const unsigned short* bp0 = WT + (size_t)(c0 + r) * 256 + seg * 8;
        const unsigned short* bp1 = WT + (size_t)(c0 + 16 + r) * 256 + seg * 8;
#pragma unroll
        for (int kk = 0; kk < 8; ++kk) {
            bf0[kk] = *(const bf16x8*)(bp0 + kk * 32);
            bf1[kk] = *(const bf16x8*)(bp1 + kk * 32);
        }
    }
    const float bias0 = bl[c0 + r];
    const float bias1 = bl[c0 + 16 + r];

    const int tend = min((int)(blockIdx.x + 1) * TPB, NTILES);
#pragma unroll 1
    for (int t = blockIdx.x * TPB; t < tend; ++t) {
        const int row0 = t * 16;
        const unsigned short* ap = A + (size_t)(row0 + r) * 256 + seg * 8;

        bf16x8 af[8];
#pragma unroll
        for (int kk = 0; kk < 8; ++kk) af[kk] = *(const bf16x8*)(ap + kk * 32);

        f32x4 acc0 = {0.f, 0.f, 0.f, 0.f};
        f32x4 acc1 = {0.f, 0.f, 0.f, 0.f};
#pragma unroll
        for (int kk = 0; kk < 8; ++kk) {
            acc0 = __builtin_amdgcn_mfma_f32_16x16x32_bf16(af[kk], bf0[kk], acc0, 0, 0, 0);
            acc1 = __builtin_amdgcn_mfma_f32_16x16x32_bf16(af[kk], bf1[kk], acc1, 0, 0, 0);
        }

        // C/D layout: col = lane&15, row = (lane>>4)*4 + q  [m89-verified]
        float p[4];
#pragma unroll
        for (int q = 0; q < 4; ++q) {
            acc0[q] += bias0;
            acc1[q] += bias1;
            p[q] = acc0[q] * acc0[q] + acc1[q] * acc1[q];
        }
#pragma unroll
        for (int m = 1; m < 16; m <<= 1) {
#pragma unroll
            for (int q = 0; q < 4; ++q) p[q] += __shfl_xor(p[q], m);
        }
        if (r == 0) {
#pragma unroll
            for (int q = 0; q < 4; ++q) partial[wave][seg * 4 + q] = p[q];
        }
        __syncthreads();

#pragma unroll
        for (int q = 0; q < 4; ++q) {
            const int rr = seg * 4 + q;
            float s = partial[0][rr] + partial[1][rr] + partial[2][rr] + partial[3][rr];
            float inv = 1.0f / fmaxf(sqrtf(s), 1e-12f);
            float* orow = out + (size_t)(row0 + rr) * DD;
            orow[c0 + r]      = acc0[q] * inv;
            orow[c0 + 16 + r] = acc1[q] * inv;
        }
        __syncthreads();
    }
}

extern "C" void kernel_launch(void* const* d_in, const int* in_sizes, int n_in,
                              void* d_out, int out_size, void* d_ws, size_t ws_size,
                              hipStream_t stream) {
    const float* x        = (const float*)d_in[0];
    const int*   ei       = (const int*)d_in[1];
    const float* Wl2      = (const float*)d_in[5];
    const float* bl2      = (const float*)d_in[6];
    const float* Wr2      = (const float*)d_in[7];
    const float* bn_gamma = (const float*)d_in[8];
    const float* bn_beta  = (const float*)d_in[9];
    const float* bn_mean  = (const float*)d_in[10];
    const float* bn_var   = (const float*)d_in[11];
    float* out = (float*)d_out;

    // workspace layout
    unsigned short* A  = (unsigned short*)d_ws;             // NN*256 bf16 (51.2 MB)
    unsigned short* WT = A + (size_t)NN * 256;              // 64 KB
    int* cursor = (int*)(WT + DD * 256);                    // NBIN
    int* slab   = cursor + NBIN;                            // NBIN*BCAP (3.6 MB)

    hipMemsetAsync(cursor, 0, NBIN * sizeof(int), stream);
    sort_wt_kernel<<<SORTB + 128, 256, 0, stream>>>(ei, Wl2, Wr2, WT, cursor, slab);
    bin_aggregate_kernel<<<NBIN, 256, 0, stream>>>(
        x, cursor, slab, bn_gamma, bn_beta, bn_mean, bn_var, A);
    mfma_gemm_norm_kernel<<<(NTILES + TPB - 1) / TPB, 256, 0, stream>>>(A, WT, bl2, out);
}